// Round 3
// baseline (721.003 us; speedup 1.0000x reference)
//
#include <hip/hip_runtime.h>

// ---------------------------------------------------------------------------
// EdgeFeatures (fp32 in / fp32 out):
//   out[i] = (e[i] @ Us_w^T + Us_b) + Vx[src[i]] + Vx[dst[i]]
//   Vx     = x @ Vs_w^T + Vs_b
// H=256, V=10000, E=300000.
// Round-3 structure: BARRIER-FREE, LDS-FREE GEMM. K=256 is tiny, weights are
// L2-resident -> each wave loads MFMA fragments straight from global:
//   A: fp32 2xf32x4 per frag (register prefetch 1 K-iter ahead), cvt->bf16
//   B: bf16x8 per frag from pre-converted weights (L2 hit)
// No __syncthreads -> no vmcnt(0) drains -> loads pipeline freely. This
// removes the m97-structure barrier stall that capped round 2 at 2.6 TB/s.
// Block = 64 rows x N=256 (4 waves, one 64-col quarter each).
// ws layout: [0,128K) Us_w bf16 | [128K,256K) Vs_w bf16 | [256K,+5.12M) Vx bf16
// ---------------------------------------------------------------------------

typedef __bf16 bf16_t;
typedef __bf16 bf16x4 __attribute__((ext_vector_type(4)));
typedef __bf16 bf16x8 __attribute__((ext_vector_type(8)));
typedef float f32x4 __attribute__((ext_vector_type(4)));
typedef float f32x8 __attribute__((ext_vector_type(8)));

#define HDIM 256
#define NV 10000
#define NE 300000

// fp32 -> bf16 convert of both 256x256 weight matrices (65536 elems each)
__global__ __launch_bounds__(256) void cvt_weights(
    const float* __restrict__ us, const float* __restrict__ vs,
    bf16_t* __restrict__ us_o, bf16_t* __restrict__ vs_o) {
  const int i = (blockIdx.x * 256 + threadIdx.x) * 4;  // 64 blocks cover 65536
  f32x4 a = *(const f32x4*)(us + i);
  f32x4 b = *(const f32x4*)(vs + i);
  *(bf16x4*)(us_o + i) = __builtin_convertvector(a, bf16x4);
  *(bf16x4*)(vs_o + i) = __builtin_convertvector(b, bf16x4);
}

template <bool FUSED>
__global__ __launch_bounds__(256) void gemm(
    const float* __restrict__ A,     // M x 256 fp32 (e or x)
    const bf16_t* __restrict__ Wb,   // 256 x 256 bf16 row-major [n][k]
    const float* __restrict__ bias,  // 256 fp32
    const int* __restrict__ sIdxG,   // FUSED: src indices (E)
    const int* __restrict__ dIdxG,   // FUSED: dst indices (E)
    const bf16_t* __restrict__ Vx,   // FUSED: V x 256 bf16
    float* __restrict__ outF,        // FUSED: M x 256 fp32
    bf16_t* __restrict__ outB,       // !FUSED: M x 256 bf16 (Vx scratch)
    int M) {
  const int tid = threadIdx.x;   // 0..255
  const int lane = tid & 63;
  const int wn = tid >> 6;       // wave = n-quarter 0..3
  const int l15 = lane & 15;
  const int quad = lane >> 4;    // 0..3

  const int row0 = blockIdx.x * 64;

  // --- fragment global pointers --------------------------------------------
  // A-operand layout: A[m = lane&15][k = quad*8 + j], frag mi covers rows
  // row0 + mi*16 + l15; lane reads 8 consecutive fp32 at k = k0 + quad*8.
  const float* gA[4];
#pragma unroll
  for (int mi = 0; mi < 4; ++mi) {
    int r = row0 + mi * 16 + l15;
    if (r >= M) r = M - 1;  // clamp: harmless duplicate reads on tail block
    gA[mi] = A + (size_t)r * HDIM + quad * 8;
  }
  // B-operand layout: B[n = lane&15][k = quad*8 + j]; frag ni covers
  // n = wn*64 + ni*16 + l15. One bf16x8 (16 B) per frag, L2-resident.
  const bf16_t* gB[4];
#pragma unroll
  for (int ni = 0; ni < 4; ++ni)
    gB[ni] = Wb + (size_t)(wn * 64 + ni * 16 + l15) * HDIM + quad * 8;

  f32x4 acc[4][4];
#pragma unroll
  for (int mi = 0; mi < 4; ++mi)
#pragma unroll
    for (int ni = 0; ni < 4; ++ni) {
      f32x4 z = {0.f, 0.f, 0.f, 0.f};
      acc[mi][ni] = z;
    }

  // --- A register prefetch, 1 K-iter ahead ---------------------------------
  f32x4 pa0[4], pa1[4];
#pragma unroll
  for (int mi = 0; mi < 4; ++mi) {
    pa0[mi] = *(const f32x4*)(gA[mi] + 0);
    pa1[mi] = *(const f32x4*)(gA[mi] + 4);
  }

  for (int k0 = 0; k0 < HDIM; k0 += 32) {
    // B frags for this iter (L2 hits, pipelined by compiler via vmcnt)
    bf16x8 bfr[4];
#pragma unroll
    for (int ni = 0; ni < 4; ++ni)
      bfr[ni] = *(const bf16x8*)(gB[ni] + k0);

    // consume prefetched A, convert to bf16 frags
    bf16x8 af[4];
#pragma unroll
    for (int mi = 0; mi < 4; ++mi) {
      f32x4 c0 = pa0[mi], c1 = pa1[mi];
      f32x8 t = {c0[0], c0[1], c0[2], c0[3], c1[0], c1[1], c1[2], c1[3]};
      af[mi] = __builtin_convertvector(t, bf16x8);
    }

    // prefetch next iter's A (no barrier anywhere -> stays in flight)
    if (k0 + 32 < HDIM) {
#pragma unroll
      for (int mi = 0; mi < 4; ++mi) {
        pa0[mi] = *(const f32x4*)(gA[mi] + k0 + 32);
        pa1[mi] = *(const f32x4*)(gA[mi] + k0 + 36);
      }
    }

#pragma unroll
    for (int mi = 0; mi < 4; ++mi)
#pragma unroll
      for (int ni = 0; ni < 4; ++ni)
        acc[mi][ni] = __builtin_amdgcn_mfma_f32_16x16x32_bf16(
            af[mi], bfr[ni], acc[mi][ni], 0, 0, 0);
  }

  // --- epilogue: C/D layout col = lane&15, row = quad*4 + reg ---------------
  float bcol[4];
#pragma unroll
  for (int ni = 0; ni < 4; ++ni)
    bcol[ni] = bias[wn * 64 + ni * 16 + l15];

#pragma unroll
  for (int mi = 0; mi < 4; ++mi) {
#pragma unroll
    for (int r = 0; r < 4; ++r) {
      const int row = row0 + mi * 16 + quad * 4 + r;
      if (row < M) {
        if (FUSED) {
          const int si = sIdxG[row];
          const int di = dIdxG[row];
          const bf16_t* vs = Vx + (size_t)si * HDIM + wn * 64 + l15;
          const bf16_t* vd = Vx + (size_t)di * HDIM + wn * 64 + l15;
          float* orow = outF + (size_t)row * HDIM + wn * 64 + l15;
#pragma unroll
          for (int ni = 0; ni < 4; ++ni)
            orow[ni * 16] = acc[mi][ni][r] + bcol[ni] +
                            (float)vs[ni * 16] + (float)vd[ni * 16];
        } else {
          bf16_t* orow = outB + (size_t)row * HDIM + wn * 64 + l15;
#pragma unroll
          for (int ni = 0; ni < 4; ++ni)
            orow[ni * 16] = (bf16_t)(acc[mi][ni][r] + bcol[ni]);
        }
      }
    }
  }
}

extern "C" void kernel_launch(void* const* d_in, const int* in_sizes, int n_in,
                              void* d_out, int out_size, void* d_ws,
                              size_t ws_size, hipStream_t stream) {
  const float* x = (const float*)d_in[0];     // (V, H) fp32
  const float* e = (const float*)d_in[1];     // (E, H) fp32
  const int* edge = (const int*)d_in[2];      // (2, E) int32: src then dst
  const float* Us_w = (const float*)d_in[3];  // (H, H) fp32
  const float* Us_b = (const float*)d_in[4];  // (H,) fp32
  const float* Vs_w = (const float*)d_in[5];  // (H, H) fp32
  const float* Vs_b = (const float*)d_in[6];  // (H,) fp32
  float* out = (float*)d_out;                 // (E, H) fp32

  bf16_t* us_w_b = (bf16_t*)d_ws;                         // 128 KB
  bf16_t* vs_w_b = (bf16_t*)((char*)d_ws + (128 << 10));  // 128 KB
  bf16_t* Vx = (bf16_t*)((char*)d_ws + (256 << 10));      // 5.12 MB

  dim3 blk(256, 1, 1);

  cvt_weights<<<dim3(64, 1, 1), blk, 0, stream>>>(Us_w, Vs_w, us_w_b, vs_w_b);

  dim3 g1((NV + 63) / 64, 1, 1);
  gemm<false><<<g1, blk, 0, stream>>>(x, vs_w_b, Vs_b, nullptr, nullptr,
                                      nullptr, nullptr, Vx, NV);

  dim3 g2((NE + 63) / 64, 1, 1);
  gemm<true><<<g2, blk, 0, stream>>>(e, us_w_b, Us_b, edge, edge + NE, Vx, out,
                                     nullptr, NE);
}